// Round 2
// baseline (2215.340 us; speedup 1.0000x reference)
//
#include <hip/hip_runtime.h>
#include <math.h>

static constexpr int T_LEN  = 1024;
static constexpr int B_SZ   = 32;
static constexpr int I_SZ   = 1024;
static constexpr int H_SZ   = 256;
static constexpr int M_ROWS = B_SZ * T_LEN;   // 32768 rows = (b,t) flattened

// ---------------------------------------------------------------------------
// Projection GEMM:  C[z, m, n] = sum_k A[m,k] * Bw[z,n,k] + bih[z,n] + bhh[z,n]
// A: (M_ROWS, K) row-major.  Bw: (2, H_SZ, K).  C: (2, M_ROWS, H_SZ).
// BM=BN=128, BK=32, 256 threads, 8x8 accumulator per thread.
// grid: (M_ROWS/128, H_SZ/128 = 2, 2 directions)
// FMA-bound by analysis: per kk per CU ~512 FMA-cycles vs ~96 LDS bank-cycles
// (a-reads are 16-distinct-address broadcasts, b-reads 4).
// ---------------------------------------------------------------------------
__global__ __launch_bounds__(256, 2)   // (256,4) risks VGPR spill at 128-cap
void proj_gemm(const float* __restrict__ A, int K,
               const float* __restrict__ Bw,
               const float* __restrict__ bih,
               const float* __restrict__ bhh,
               float* __restrict__ C)
{
    __shared__ float As[32][132];   // [k][m], +4 pad words per row
    __shared__ float Bs[32][132];   // [k][n]

    const int tid = threadIdx.x;
    const int m0  = blockIdx.x * 128;
    const int n0  = blockIdx.y * 128;
    const int z   = blockIdx.z;

    const float* Bz = Bw + (size_t)z * H_SZ * K;
    float*       Cz = C  + (size_t)z * M_ROWS * H_SZ;

    const int lr = tid >> 3;        // 0..31 (row within 32-row stripe)
    const int lc = (tid & 7) * 4;   // 0..28 (k column quad)

    const int tm = tid & 15;        // m-group (8 rows each)
    const int tn = tid >> 4;        // n-group (8 cols each)

    float acc[8][8];
    #pragma unroll
    for (int i = 0; i < 8; ++i)
        #pragma unroll
        for (int j = 0; j < 8; ++j) acc[i][j] = 0.f;

    for (int k0 = 0; k0 < K; k0 += 32) {
        #pragma unroll
        for (int r = 0; r < 4; ++r) {
            const int row = r * 32 + lr;
            float4 av = *(const float4*)(A  + (size_t)(m0 + row) * K + k0 + lc);
            As[lc + 0][row] = av.x; As[lc + 1][row] = av.y;
            As[lc + 2][row] = av.z; As[lc + 3][row] = av.w;
            float4 bv = *(const float4*)(Bz + (size_t)(n0 + row) * K + k0 + lc);
            Bs[lc + 0][row] = bv.x; Bs[lc + 1][row] = bv.y;
            Bs[lc + 2][row] = bv.z; Bs[lc + 3][row] = bv.w;
        }
        __syncthreads();
        #pragma unroll
        for (int kk = 0; kk < 32; ++kk) {
            float a[8], b[8];
            *(float4*)&a[0] = *(const float4*)&As[kk][tm * 8];
            *(float4*)&a[4] = *(const float4*)&As[kk][tm * 8 + 4];
            *(float4*)&b[0] = *(const float4*)&Bs[kk][tn * 8];
            *(float4*)&b[4] = *(const float4*)&Bs[kk][tn * 8 + 4];
            #pragma unroll
            for (int i = 0; i < 8; ++i)
                #pragma unroll
                for (int j = 0; j < 8; ++j)
                    acc[i][j] = fmaf(a[i], b[j], acc[i][j]);
        }
        __syncthreads();
    }

    float bsum[8];
    #pragma unroll
    for (int j = 0; j < 8; ++j) {
        const int n = n0 + tn * 8 + j;
        bsum[j] = bih[z * H_SZ + n] + bhh[z * H_SZ + n];
    }
    #pragma unroll
    for (int i = 0; i < 8; ++i) {
        const int m = m0 + tm * 8 + i;
        float4 v0, v1;
        v0.x = acc[i][0] + bsum[0]; v0.y = acc[i][1] + bsum[1];
        v0.z = acc[i][2] + bsum[2]; v0.w = acc[i][3] + bsum[3];
        v1.x = acc[i][4] + bsum[4]; v1.y = acc[i][5] + bsum[5];
        v1.z = acc[i][6] + bsum[6]; v1.w = acc[i][7] + bsum[7];
        *(float4*)(Cz + (size_t)m * H_SZ + n0 + tn * 8)     = v0;
        *(float4*)(Cz + (size_t)m * H_SZ + n0 + tn * 8 + 4) = v1;
    }
}

// ---------------------------------------------------------------------------
// Recurrent scan. One workgroup per (direction d, batch b) chain.
// h_t = tanh(xp_t + Whh[d] @ h_{t-1}), h_{-1} = 0, backward for d=1.
// 512 threads = 64 output-quads (4 rows of Whh each) x 8 k-groups (32 k each).
// Whh slice register-resident (128 VGPR/thread). h broadcast via padded LDS
// (8 distinct b128 addresses per read slot -> disjoint bank-quads, no
// conflict). Reduction over the 8 k-groups: 3-stage shfl_xor butterfly
// (lane bits 0..2). Double-buffered hbuf -> ONE barrier per step. tanh
// finalization spread over lanes g<4 (one element each) via the exact
// identity tanh(v) = 1 - 2/(exp(2v)+1)  (~6 VALU instrs, abs err ~1e-7).
// ---------------------------------------------------------------------------
__global__ __launch_bounds__(512)
void rnn_scan(const float* __restrict__ xp,   // (2, B, T, H)
              const float* __restrict__ Whh,  // (2, H, H)
              float* __restrict__ out)        // (B, T, 2H)
{
    const int tid = threadIdx.x;
    const int d = blockIdx.x >> 5;
    const int b = blockIdx.x & 31;
    const int g = tid & 7;    // k-group: k in [g*32, g*32+32)
    const int q = tid >> 3;   // output quad: j in [4q, 4q+4)

    const float* xpc  = xp  + (size_t)(d * B_SZ + b) * T_LEN * H_SZ;
    const float* W    = Whh + (size_t)d * H_SZ * H_SZ;
    float*       outc = out + (size_t)b * T_LEN * (2 * H_SZ) + d * H_SZ;

    // register-resident Whh slice: w[jj][kk] = W[4q+jj][g*32+kk]
    float w[4][32];
    #pragma unroll
    for (int jj = 0; jj < 4; ++jj) {
        const float* wrow = W + (size_t)(4 * q + jj) * H_SZ + g * 32;
        #pragma unroll
        for (int c = 0; c < 8; ++c)
            *(float4*)&w[jj][c * 4] = *(const float4*)(wrow + c * 4);
    }

    // double-buffered padded h: word index(k) = k + (k>>5)*4
    __shared__ float hbuf[2][288];
    for (int i = tid; i < 2 * 288; i += 512) ((float*)hbuf)[i] = 0.f;

    int t = d ? (T_LEN - 1) : 0;
    const int dt = d ? -1 : 1;
    const int elem = 4 * q + g;            // element owned by lanes g<4

    float xpv = 0.f;
    if (g < 4) xpv = xpc[(size_t)t * H_SZ + elem];
    __syncthreads();

    int p = 0;
    for (int s = 0; s < T_LEN; ++s) {
        const int tnext = t + dt;
        // prefetch next step's xp; latency hides under the FMA loop
        float xpn = 0.f;
        if (g < 4 && s + 1 < T_LEN)
            xpn = xpc[(size_t)tnext * H_SZ + elem];

        const float* hb = hbuf[p];
        float acc[4] = {0.f, 0.f, 0.f, 0.f};
        #pragma unroll
        for (int c = 0; c < 8; ++c) {
            float4 hv = *(const float4*)&hb[g * 36 + 4 * c];
            #pragma unroll
            for (int jj = 0; jj < 4; ++jj) {
                acc[jj] = fmaf(w[jj][4 * c + 0], hv.x, acc[jj]);
                acc[jj] = fmaf(w[jj][4 * c + 1], hv.y, acc[jj]);
                acc[jj] = fmaf(w[jj][4 * c + 2], hv.z, acc[jj]);
                acc[jj] = fmaf(w[jj][4 * c + 3], hv.w, acc[jj]);
            }
        }
        // butterfly reduce over the 8 k-groups (lane bits 0..2)
        #pragma unroll
        for (int m = 1; m < 8; m <<= 1) {
            #pragma unroll
            for (int jj = 0; jj < 4; ++jj)
                acc[jj] += __shfl_xor(acc[jj], m, 64);
        }
        if (g < 4) {
            const float v = acc[g] + xpv;
            const float e = __expf(2.f * v);       // exact: tanh(v)=1-2/(e+1)
            const float h = 1.f - 2.f / (e + 1.f);
            hbuf[p ^ 1][elem + ((elem >> 5) << 2)] = h;
            outc[(size_t)t * (2 * H_SZ) + elem] = h;
        }
        __syncthreads();   // orders: writes of buf p^1 vs next step's reads,
                           // and this step's reads of buf p vs step s+1 writes
        p ^= 1;
        xpv = xpn;
        t = tnext;
    }
}

// ---------------------------------------------------------------------------
extern "C" void kernel_launch(void* const* d_in, const int* in_sizes, int n_in,
                              void* d_out, int out_size, void* d_ws, size_t ws_size,
                              hipStream_t stream)
{
    (void)in_sizes; (void)n_in; (void)out_size; (void)ws_size;

    const float* x    = (const float*)d_in[0];
    const float* Wih0 = (const float*)d_in[1];
    const float* Whh0 = (const float*)d_in[2];
    const float* bih0 = (const float*)d_in[3];
    const float* bhh0 = (const float*)d_in[4];
    const float* Wih1 = (const float*)d_in[5];
    const float* Whh1 = (const float*)d_in[6];
    const float* bih1 = (const float*)d_in[7];
    const float* bhh1 = (const float*)d_in[8];

    float* out = (float*)d_out;        // (B, T, 2H); also holds layer-0 hs
    float* XP  = (float*)d_ws;         // (2, B, T, H) fp32 = 64 MiB, reused

    dim3 ggrid(M_ROWS / 128, 2, 2);

    // layer 0
    proj_gemm<<<ggrid, 256, 0, stream>>>(x, I_SZ, Wih0, bih0, bhh0, XP);
    rnn_scan<<<64, 512, 0, stream>>>(XP, Whh0, out);
    // layer 1 (reads layer-0 hs from d_out, XP buffer reused)
    proj_gemm<<<ggrid, 256, 0, stream>>>(out, 2 * H_SZ, Wih1, bih1, bhh1, XP);
    rnn_scan<<<64, 512, 0, stream>>>(XP, Whh1, out);
}

// Round 5
// 2024.222 us; speedup vs baseline: 1.0944x; 1.0944x over previous
//
#include <hip/hip_runtime.h>
#include <math.h>

static constexpr int T_LEN  = 1024;
static constexpr int B_SZ   = 32;
static constexpr int I_SZ   = 1024;
static constexpr int H_SZ   = 256;
static constexpr int M_ROWS = B_SZ * T_LEN;   // 32768 rows = (b,t) flattened

// ---------------------------------------------------------------------------
// Projection GEMM (unchanged, known-good):
// C[z, m, n] = sum_k A[m,k] * Bw[z,n,k] + bih[z,n] + bhh[z,n]
// ---------------------------------------------------------------------------
__global__ __launch_bounds__(256, 2)
void proj_gemm(const float* __restrict__ A, int K,
               const float* __restrict__ Bw,
               const float* __restrict__ bih,
               const float* __restrict__ bhh,
               float* __restrict__ C)
{
    __shared__ float As[32][132];   // [k][m], +4 pad words per row
    __shared__ float Bs[32][132];   // [k][n]

    const int tid = threadIdx.x;
    const int m0  = blockIdx.x * 128;
    const int n0  = blockIdx.y * 128;
    const int z   = blockIdx.z;

    const float* Bz = Bw + (size_t)z * H_SZ * K;
    float*       Cz = C  + (size_t)z * M_ROWS * H_SZ;

    const int lr = tid >> 3;        // 0..31
    const int lc = (tid & 7) * 4;   // 0..28

    const int tm = tid & 15;        // m-group (8 rows each)
    const int tn = tid >> 4;        // n-group (8 cols each)

    float acc[8][8];
    #pragma unroll
    for (int i = 0; i < 8; ++i)
        #pragma unroll
        for (int j = 0; j < 8; ++j) acc[i][j] = 0.f;

    for (int k0 = 0; k0 < K; k0 += 32) {
        #pragma unroll
        for (int r = 0; r < 4; ++r) {
            const int row = r * 32 + lr;
            float4 av = *(const float4*)(A  + (size_t)(m0 + row) * K + k0 + lc);
            As[lc + 0][row] = av.x; As[lc + 1][row] = av.y;
            As[lc + 2][row] = av.z; As[lc + 3][row] = av.w;
            float4 bv = *(const float4*)(Bz + (size_t)(n0 + row) * K + k0 + lc);
            Bs[lc + 0][row] = bv.x; Bs[lc + 1][row] = bv.y;
            Bs[lc + 2][row] = bv.z; Bs[lc + 3][row] = bv.w;
        }
        __syncthreads();
        #pragma unroll
        for (int kk = 0; kk < 32; ++kk) {
            float a[8], b[8];
            *(float4*)&a[0] = *(const float4*)&As[kk][tm * 8];
            *(float4*)&a[4] = *(const float4*)&As[kk][tm * 8 + 4];
            *(float4*)&b[0] = *(const float4*)&Bs[kk][tn * 8];
            *(float4*)&b[4] = *(const float4*)&Bs[kk][tn * 8 + 4];
            #pragma unroll
            for (int i = 0; i < 8; ++i)
                #pragma unroll
                for (int j = 0; j < 8; ++j)
                    acc[i][j] = fmaf(a[i], b[j], acc[i][j]);
        }
        __syncthreads();
    }

    float bsum[8];
    #pragma unroll
    for (int j = 0; j < 8; ++j) {
        const int n = n0 + tn * 8 + j;
        bsum[j] = bih[z * H_SZ + n] + bhh[z * H_SZ + n];
    }
    #pragma unroll
    for (int i = 0; i < 8; ++i) {
        const int m = m0 + tm * 8 + i;
        float4 v0, v1;
        v0.x = acc[i][0] + bsum[0]; v0.y = acc[i][1] + bsum[1];
        v0.z = acc[i][2] + bsum[2]; v0.w = acc[i][3] + bsum[3];
        v1.x = acc[i][4] + bsum[4]; v1.y = acc[i][5] + bsum[5];
        v1.z = acc[i][6] + bsum[6]; v1.w = acc[i][7] + bsum[7];
        *(float4*)(Cz + (size_t)m * H_SZ + n0 + tn * 8)     = v0;
        *(float4*)(Cz + (size_t)m * H_SZ + n0 + tn * 8 + 4) = v1;
    }
}

// ---------------------------------------------------------------------------
// DPP butterfly helper: lane i receives value from lane i^1 / i^2 (VALU pipe,
// no LDS). quad_perm[1,0,3,2]=0xB1, quad_perm[2,3,0,1]=0x4E.
// ---------------------------------------------------------------------------
__device__ __forceinline__ float dpp_xor1(float x) {
    return __int_as_float(__builtin_amdgcn_mov_dpp(__float_as_int(x), 0xB1, 0xf, 0xf, true));
}
__device__ __forceinline__ float dpp_xor2(float x) {
    return __int_as_float(__builtin_amdgcn_mov_dpp(__float_as_int(x), 0x4E, 0xf, 0xf, true));
}

// ---------------------------------------------------------------------------
// Recurrent scan. One WG per (direction d, batch b) chain; 64 WGs total.
// h_t = tanh(xp_t + Whh[d] @ h_{t-1}), h_{-1}=0, backward for d=1.
// 512 threads = 128 row-pairs (q) x 4 k-groups (g, 64 k each).
// Thread (q,g): rows {2q,2q+1}, k in [64g,64g+64); W slice = 128 VGPR.
// __launch_bounds__(512,2): 8 waves/WG = 2 waves/SIMD -> VGPR cap 256, so
// the W slice actually STAYS register-resident (round-2's bare (512) gave
// VGPR_Count=84 -> compiler streamed W from L2 every step, ~16 GB/scan).
// Reduction over the 4 k-groups: xor1+xor2 quad_perm DPP adds (no LDS, no
// shfl). After the butterfly ALL lanes hold full sums -> branch-free tanh.
// h broadcast via padded LDS: word(k) = k + (k>>6)*4, so the 4 distinct b128
// addresses per wave-read occupy disjoint bank-quads (conflict-free).
// Double-buffered h -> ONE barrier per step.
// tanh(v) = 1 - 2/(exp(2v)+1) (exact identity, __expf ~1e-7 abs err).
// ---------------------------------------------------------------------------
__global__ __launch_bounds__(512, 2)
void rnn_scan(const float* __restrict__ xp,   // (2, B, T, H)
              const float* __restrict__ Whh,  // (2, H, H)
              float* __restrict__ out)        // (B, T, 2H)
{
    const int tid = threadIdx.x;
    const int d = blockIdx.x >> 5;
    const int b = blockIdx.x & 31;
    const int g = tid & 3;    // k-group: k in [g*64, g*64+64)
    const int q = tid >> 2;   // row-pair: rows {2q, 2q+1}

    const float* xpc  = xp  + (size_t)(d * B_SZ + b) * T_LEN * H_SZ;
    const float* W    = Whh + (size_t)d * H_SZ * H_SZ;
    float*       outc = out + (size_t)b * T_LEN * (2 * H_SZ) + d * H_SZ;

    // register-resident Whh slice: w4[r][c] = W[2q+r][64g+4c .. +3]
    float4 w4[2][16];
    #pragma unroll
    for (int r = 0; r < 2; ++r) {
        const float* wrow = W + (size_t)(2 * q + r) * H_SZ + g * 64;
        #pragma unroll
        for (int c = 0; c < 16; ++c)
            w4[r][c] = *(const float4*)(wrow + 4 * c);
    }

    // double-buffered padded h: word(k) = k + (k>>6)*4  (268 used, 272 alloc)
    __shared__ float hbuf[2][272];
    for (int i = tid; i < 2 * 272; i += 512) ((float*)hbuf)[i] = 0.f;

    int t = d ? (T_LEN - 1) : 0;
    const int dt = d ? -1 : 1;

    // xp for rows {2q,2q+1}; 4 lanes per quad read the same address (bcast)
    float2 xpv = *(const float2*)(xpc + (size_t)t * H_SZ + 2 * q);
    __syncthreads();

    int p = 0;
    for (int s = 0; s < T_LEN; ++s) {
        const int tnext = t + dt;
        float2 xpn = make_float2(0.f, 0.f);
        if (s + 1 < T_LEN)
            xpn = *(const float2*)(xpc + (size_t)tnext * H_SZ + 2 * q);

        const float* hb = hbuf[p];
        float a0 = 0.f, a1 = 0.f;
        #pragma unroll
        for (int c = 0; c < 16; ++c) {
            // word(64g+4c) = 68g + 4c  (4c < 64 never crosses a pad block)
            float4 hv = *(const float4*)&hb[68 * g + 4 * c];
            a0 = fmaf(w4[0][c].x, hv.x, a0);
            a0 = fmaf(w4[0][c].y, hv.y, a0);
            a0 = fmaf(w4[0][c].z, hv.z, a0);
            a0 = fmaf(w4[0][c].w, hv.w, a0);
            a1 = fmaf(w4[1][c].x, hv.x, a1);
            a1 = fmaf(w4[1][c].y, hv.y, a1);
            a1 = fmaf(w4[1][c].z, hv.z, a1);
            a1 = fmaf(w4[1][c].w, hv.w, a1);
        }
        // allreduce over the 4 k-groups (lane bits 0,1) — pure DPP
        a0 += dpp_xor1(a0);  a1 += dpp_xor1(a1);
        a0 += dpp_xor2(a0);  a1 += dpp_xor2(a1);

        // branch-free finalize on ALL lanes (redundant x4, no divergence)
        const float v0 = a0 + xpv.x;
        const float v1 = a1 + xpv.y;
        const float h0 = 1.f - 2.f / (__expf(2.f * v0) + 1.f);
        const float h1 = 1.f - 2.f / (__expf(2.f * v1) + 1.f);

        if (g == 0) {
            // word(2q) = 2q + ((q>>5)<<2); 2q,2q+1 always in the same block
            *(float2*)&hbuf[p ^ 1][2 * q + ((q >> 5) << 2)] = make_float2(h0, h1);
            *(float2*)(outc + (size_t)t * (2 * H_SZ) + 2 * q) = make_float2(h0, h1);
        }
        __syncthreads();   // publishes buf p^1; protects buf p until read
        p ^= 1;
        xpv = xpn;
        t = tnext;
    }
}

// ---------------------------------------------------------------------------
extern "C" void kernel_launch(void* const* d_in, const int* in_sizes, int n_in,
                              void* d_out, int out_size, void* d_ws, size_t ws_size,
                              hipStream_t stream)
{
    (void)in_sizes; (void)n_in; (void)out_size; (void)ws_size;

    const float* x    = (const float*)d_in[0];
    const float* Wih0 = (const float*)d_in[1];
    const float* Whh0 = (const float*)d_in[2];
    const float* bih0 = (const float*)d_in[3];
    const float* bhh0 = (const float*)d_in[4];
    const float* Wih1 = (const float*)d_in[5];
    const float* Whh1 = (const float*)d_in[6];
    const float* bih1 = (const float*)d_in[7];
    const float* bhh1 = (const float*)d_in[8];

    float* out = (float*)d_out;        // (B, T, 2H); also holds layer-0 hs
    float* XP  = (float*)d_ws;         // (2, B, T, H) fp32 = 64 MiB, reused

    dim3 ggrid(M_ROWS / 128, 2, 2);

    // layer 0
    proj_gemm<<<ggrid, 256, 0, stream>>>(x, I_SZ, Wih0, bih0, bhh0, XP);
    rnn_scan<<<64, 512, 0, stream>>>(XP, Whh0, out);
    // layer 1 (reads layer-0 hs from d_out, XP buffer reused)
    proj_gemm<<<ggrid, 256, 0, stream>>>(out, 2 * H_SZ, Wih1, bih1, bhh1, XP);
    rnn_scan<<<64, 512, 0, stream>>>(XP, Whh1, out);
}